// Round 2
// baseline (649.329 us; speedup 1.0000x reference)
//
#include <hip/hip_runtime.h>

// GlobalContrastiveLoss, B=131072, D=512, N=1, fp32 in, fp32 scalar out.
// N==1 => loss_b = log1p(exp((dn-dp)/50)), dn-dp = sum_d img*(neg-pos).
// Memory-bound floor: 805 MB read -> ~128 us at 6.3 TB/s.
//
// R1 post-mortem: 64-lane-per-row + 12-step shuffle chain was latency-bound
// (202 us, VALUBusy 16%, HBM 25%). This version: 16-lane groups, 4 rows per
// wave-iteration, diff-only reduction (4 shuffle steps / 4 rows), 24 loads
// in flight per wave.

#define BLOCK 256
#define WAVES_PER_BLOCK (BLOCK / 64)
#define NBLOCKS 2048
#define DCOLS 512
#define F4_PER_ROW (DCOLS / 4)   // 128

__global__ __launch_bounds__(BLOCK) void gcl_partial_kernel(
    const float* __restrict__ img,
    const float* __restrict__ pos,
    const float* __restrict__ neg,
    float* __restrict__ partials,
    int B)
{
    const int lane = threadIdx.x & 63;
    const int wave = threadIdx.x >> 6;
    const int t = lane & 15;   // position within 16-lane group
    const int g = lane >> 4;   // group 0..3 -> row within group-of-4

    const int gwave  = blockIdx.x * WAVES_PER_BLOCK + wave;
    const int nwaves = gridDim.x * WAVES_PER_BLOCK;
    const int ngroups = (B + 3) >> 2;   // groups of 4 rows

    float acc = 0.0f;

    for (int grp = gwave; grp < ngroups; grp += nwaves) {
        const int row = grp * 4 + g;
        float diff = 0.0f;
        if (row < B) {
            const float4* i4 = (const float4*)img + (size_t)row * F4_PER_ROW + t;
            const float4* p4 = (const float4*)pos + (size_t)row * F4_PER_ROW + t;
            const float4* n4 = (const float4*)neg + (size_t)row * F4_PER_ROW + t;
            // 8 float4 per lane per array: 16 lanes x 8 = 128 float4 = full row.
            #pragma unroll
            for (int j = 0; j < 8; ++j) {
                float4 a = i4[16 * j];
                float4 b = p4[16 * j];
                float4 c = n4[16 * j];
                diff += a.x * (c.x - b.x) + a.y * (c.y - b.y)
                      + a.z * (c.z - b.z) + a.w * (c.w - b.w);
            }
        }
        // Reduce within the 16-lane group (offsets < 16 stay intra-row).
        #pragma unroll
        for (int off = 1; off < 16; off <<= 1)
            diff += __shfl_xor(diff, off, 64);

        if (t == 0 && row < B)
            acc += log1pf(__expf(diff * 0.02f));
    }

    // acc lives on lanes 0,16,32,48 of each wave; fold to lane 0.
    acc += __shfl_xor(acc, 16, 64);
    acc += __shfl_xor(acc, 32, 64);

    __shared__ float sacc[WAVES_PER_BLOCK];
    if (lane == 0) sacc[wave] = acc;
    __syncthreads();

    if (threadIdx.x == 0) {
        float s = 0.0f;
        #pragma unroll
        for (int w = 0; w < WAVES_PER_BLOCK; ++w) s += sacc[w];
        partials[blockIdx.x] = s;
    }
}

__global__ __launch_bounds__(256) void gcl_final_kernel(
    const float* __restrict__ partials, int n, float* __restrict__ out, float invB)
{
    __shared__ float s[256];
    float a = 0.0f;
    for (int i = threadIdx.x; i < n; i += 256) a += partials[i];
    s[threadIdx.x] = a;
    __syncthreads();
    #pragma unroll
    for (int stride = 128; stride > 0; stride >>= 1) {
        if (threadIdx.x < stride) s[threadIdx.x] += s[threadIdx.x + stride];
        __syncthreads();
    }
    if (threadIdx.x == 0) out[0] = s[0] * invB;
}

extern "C" void kernel_launch(void* const* d_in, const int* in_sizes, int n_in,
                              void* d_out, int out_size, void* d_ws, size_t ws_size,
                              hipStream_t stream) {
    const float* img = (const float*)d_in[0];
    const float* pos = (const float*)d_in[1];
    const float* neg = (const float*)d_in[2];
    float* out = (float*)d_out;
    float* partials = (float*)d_ws;

    const int B = in_sizes[0] / DCOLS;  // N == 1

    int nblocks = NBLOCKS;
    if (ws_size < (size_t)nblocks * sizeof(float)) {
        nblocks = (int)(ws_size / sizeof(float));
        if (nblocks < 1) nblocks = 1;
    }

    gcl_partial_kernel<<<nblocks, BLOCK, 0, stream>>>(img, pos, neg, partials, B);
    gcl_final_kernel<<<1, 256, 0, stream>>>(partials, nblocks, out, 1.0f / (float)B);
}